// Round 6
// baseline (6924.583 us; speedup 1.0000x reference)
//
#include <hip/hip_runtime.h>

#define RD     128
#define TT     128
#define TLEN   16384
#define NB     8
#define NLAYER 63
#define N0SKIP 27
#define NSKIP  36
#define QD     256
#define PADR   136   // LDS row stride in bf16 elems
#define CROWS  192   // staging window rows: 52,224 B -> 3 blocks/CU

typedef short bf16x8 __attribute__((ext_vector_type(8)));
typedef float f32x4  __attribute__((ext_vector_type(4)));

__device__ __forceinline__ unsigned short f2bf(float f) {
  unsigned u = __float_as_uint(f);
  u += 0x7fffu + ((u >> 16) & 1u);
  return (unsigned short)(u >> 16);
}
__device__ __forceinline__ unsigned short f2bf_relu(float f) {
  f = f > 0.f ? f : 0.f;
  unsigned u = __float_as_uint(f);
  u += 0x7fffu + ((u >> 16) & 1u);
  return (unsigned short)(u >> 16);
}
__device__ __forceinline__ float bf2f(unsigned short s) {
  return __uint_as_float(((unsigned)s) << 16);
}
// packed relu on 2 bf16 in a dword
__device__ __forceinline__ unsigned relu2(unsigned v) {
  unsigned m = (v & 0x80008000u) >> 15;
  return v & ~((m << 16) - m);
}

__device__ __forceinline__ void zero_acc(f32x4 (&acc)[4][4]) {
#pragma unroll
  for (int i = 0; i < 4; ++i)
#pragma unroll
    for (int j = 0; j < 4; ++j) acc[i][j] = (f32x4){0.f, 0.f, 0.f, 0.f};
}

// ---------------------------------------------------------------------------
// 128-K GEMM on a 64c x 64t wave tile.
// ACT_A=true : D[m=t][n=c]; ACT_A=false: D[m=c][n=t]
// w : bf16 global [c_out][c_in]; sx: LDS bf16 [row][i]
// ---------------------------------------------------------------------------
template <bool ACT_A>
__device__ __forceinline__ void gemm128(const unsigned short* __restrict__ w,
                                        const short* sx, const int rows[4],
                                        int c0w, int n, int q, f32x4 (&acc)[4][4]) {
#pragma unroll
  for (int ks = 0; ks < 4; ++ks) {
    const int i0 = ks * 32 + q * 8;
    bf16x8 wf[4], af[4];
#pragma unroll
    for (int ct = 0; ct < 4; ++ct)
      wf[ct] = *(const bf16x8*)&w[(size_t)(c0w + ct * 16 + n) * RD + i0];
#pragma unroll
    for (int tt = 0; tt < 4; ++tt)
      af[tt] = *(const bf16x8*)&sx[rows[tt] * PADR + i0];
#pragma unroll
    for (int ct = 0; ct < 4; ++ct)
#pragma unroll
      for (int tt = 0; tt < 4; ++tt)
        acc[ct][tt] = ACT_A
          ? __builtin_amdgcn_mfma_f32_16x16x32_bf16(af[tt], wf[ct], acc[ct][tt], 0, 0, 0)
          : __builtin_amdgcn_mfma_f32_16x16x32_bf16(wf[ct], af[tt], acc[ct][tt], 0, 0, 0);
  }
}

// stage rows of relu(hi) (bf16 global [t][c]) into LDS [slot][i]
__device__ __forceinline__ void stage_hi(short* sx, const unsigned short* __restrict__ xg,
                                         int tstart, int nrows, int slot0, int tid) {
  const int tot = nrows << 4;
  for (int idx = tid; idx < tot; idx += 256) {
    const int r = idx >> 4, ck = (idx & 15) << 3;
    const int tg = tstart + r;
    uint4 v = {0u, 0u, 0u, 0u};
    if ((unsigned)tg < (unsigned)TLEN) v = *(const uint4*)&xg[(size_t)tg * RD + ck];
    v.x = relu2(v.x); v.y = relu2(v.y); v.z = relu2(v.z); v.w = relu2(v.w);
    *(uint4*)&sx[(slot0 + r) * PADR + ck] = v;
  }
}

// stage 128-row bf16 tile into LDS (no relu)
__device__ __forceinline__ void stage_tile(short* dst, const unsigned short* __restrict__ src,
                                           int tid) {
  for (int idx = tid; idx < 128 * 16; idx += 256) {
    const int r = idx >> 4, ck = (idx & 15) << 3;
    *(uint4*)&dst[r * PADR + ck] = *(const uint4*)&src[(size_t)r * RD + ck];
  }
}

// relu(acc + bias) -> LDS bf16 [t][c]   (ACT_A orientation)
__device__ __forceinline__ void store_act(short* sx, const f32x4 (&acc)[4][4],
                                          const float* __restrict__ bias,
                                          int c0w, int t0w, int n, int q) {
#pragma unroll
  for (int ct = 0; ct < 4; ++ct) {
    const int c = c0w + ct * 16 + n;
    const float bb = bias[c];
#pragma unroll
    for (int tt = 0; tt < 4; ++tt) {
      const int tb = t0w + tt * 16 + q * 4;
#pragma unroll
      for (int r = 0; r < 4; ++r)
        sx[(tb + r) * PADR + c] = (short)f2bf_relu(acc[ct][tt][r] + bb);
    }
  }
}

// ---------------------------------------------------------------------------
// Fused WaveNet layer. Residual master = bf16 hi/lo planes [B][T][C].
// ---------------------------------------------------------------------------
__global__ __launch_bounds__(256, 3) void layer_kernel(
    const unsigned short* __restrict__ hi_in, const unsigned short* __restrict__ lo_in,
    unsigned short* __restrict__ hi_out, unsigned short* __restrict__ lo_out,
    unsigned short* __restrict__ h_out,     // bf16 h (deferred skip) or null
    unsigned short* __restrict__ skipacc,   // bf16 skip RMW (G=0) or null
    const unsigned short* __restrict__ wconv, const float* __restrict__ bconv,
    const unsigned short* __restrict__ wdense, const float* __restrict__ bdense,
    const unsigned short* __restrict__ wskip, const float* __restrict__ bskip,
    int dil) {
  __shared__ short sx[CROWS * PADR];   // 52,224 B

  const int tid = threadIdx.x;
  const int b   = blockIdx.x >> 7;
  const int t0  = (blockIdx.x & 127) << 7;
  const int lane = tid & 63;
  const int n = lane & 15, q = lane >> 4;
  const int wv = tid >> 6;
  const int c0w = (wv & 1) * 64, t0w = (wv >> 1) * 64;
  const unsigned short* hib = hi_in + (size_t)b * TLEN * RD;

  f32x4 acc[4][4];
  zero_acc(acc);
  int rows[4];

  if (dil <= 32) {
    // window [t0-d, t0+128+d) <= 192 rows; tap k reads slot t_local + k*d
    stage_hi(sx, hib, t0 - dil, 128 + 2 * dil, 0, tid);
    __syncthreads();
#pragma unroll
    for (int k = 0; k < 3; ++k) {
#pragma unroll
      for (int tt = 0; tt < 4; ++tt) rows[tt] = t0w + tt * 16 + n + k * dil;
      gemm128<true>(wconv + (size_t)k * RD * RD, sx, rows, c0w, n, q, acc);
    }
  } else if (dil == 64) {
    // phase A: [t0-64, t0+128) -> slots 0..191; taps 0,1
    stage_hi(sx, hib, t0 - 64, 192, 0, tid);
    __syncthreads();
#pragma unroll
    for (int tt = 0; tt < 4; ++tt) rows[tt] = t0w + tt * 16 + n;
    gemm128<true>(wconv, sx, rows, c0w, n, q, acc);
#pragma unroll
    for (int tt = 0; tt < 4; ++tt) rows[tt] = t0w + tt * 16 + n + 64;
    gemm128<true>(wconv + (size_t)RD * RD, sx, rows, c0w, n, q, acc);
    __syncthreads();
    // phase B: [t0+128, t0+192) -> slots 0..63; tap 2 at (t_local+128)%192
    stage_hi(sx, hib, t0 + 128, 64, 0, tid);
    __syncthreads();
#pragma unroll
    for (int tt = 0; tt < 4; ++tt) {
      int r = t0w + tt * 16 + n + 128;
      if (r >= CROWS) r -= CROWS;
      rows[tt] = r;
    }
    gemm128<true>(wconv + (size_t)2 * RD * RD, sx, rows, c0w, n, q, acc);
  } else {
    // d in {128,256}: sequential 128-row tap tiles
#pragma unroll
    for (int tt = 0; tt < 4; ++tt) rows[tt] = t0w + tt * 16 + n;
    for (int k = 0; k < 3; ++k) {
      if (k) __syncthreads();
      stage_hi(sx, hib, t0 + (k - 1) * dil, 128, 0, tid);
      __syncthreads();
      gemm128<true>(wconv + (size_t)k * RD * RD, sx, rows, c0w, n, q, acc);
    }
  }
  __syncthreads();

  // h = relu(conv + bconv) -> LDS rows [0,128)
  store_act(sx, acc, bconv, c0w, t0w, n, q);
  __syncthreads();

  // deferred skip: stream h tile to global (coalesced from LDS)
  if (h_out) {
    unsigned short* hb = h_out + ((size_t)b * TLEN + t0) * RD;
    for (int idx = tid; idx < 128 * 16; idx += 256) {
      const int r = idx >> 4, ck = (idx & 15) << 3;
      *(uint4*)&hb[(size_t)r * RD + ck] = *(const uint4*)&sx[r * PADR + ck];
    }
  }

  // dense GEMM + hi/lo residual
  zero_acc(acc);
#pragma unroll
  for (int tt = 0; tt < 4; ++tt) rows[tt] = t0w + tt * 16 + n;
  gemm128<true>(wdense, sx, rows, c0w, n, q, acc);
  {
    const size_t tb_g = ((size_t)b * TLEN + t0) * RD;
    const unsigned short* hi_i = hi_in + tb_g;
    const unsigned short* lo_i = lo_in + tb_g;
    unsigned short* hi_o = hi_out + tb_g;
    unsigned short* lo_o = lo_out + tb_g;
#pragma unroll
    for (int ct = 0; ct < 4; ++ct) {
      const int c = c0w + ct * 16 + n;
      const float bd = bdense[c];
#pragma unroll
      for (int tt = 0; tt < 4; ++tt) {
        const int tb = t0w + tt * 16 + q * 4;
#pragma unroll
        for (int r = 0; r < 4; ++r) {
          const size_t o = (size_t)(tb + r) * RD + c;
          const float xv = bf2f(hi_i[o]) + bf2f(lo_i[o]);
          const float v = xv + acc[ct][tt][r] + bd;
          const unsigned short hv = f2bf(v);
          hi_o[o] = hv;
          lo_o[o] = f2bf(v - bf2f(hv));
        }
      }
    }
  }

  // G=0 path: per-layer skip GEMM + bf16 RMW
  if (skipacc) {
    zero_acc(acc);
    gemm128<true>(wskip, sx, rows, c0w, n, q, acc);
    unsigned short* sp = skipacc + ((size_t)b * TLEN + t0) * RD;
#pragma unroll
    for (int ct = 0; ct < 4; ++ct) {
      const int c = c0w + ct * 16 + n;
      const float bs = bskip[c];
#pragma unroll
      for (int tt = 0; tt < 4; ++tt) {
        const int tb = t0w + tt * 16 + q * 4;
#pragma unroll
        for (int r = 0; r < 4; ++r) {
          const size_t o = (size_t)(tb + r) * RD + c;
          sp[o] = f2bf(bf2f(sp[o]) + acc[ct][tt][r] + bs);
        }
      }
    }
  }
}

// ---------------------------------------------------------------------------
// Gather: skip-sum over nl h-buffers (double-buffered), bf16 skipacc io,
// optional fused post network.
// ---------------------------------------------------------------------------
__global__ __launch_bounds__(256, 2) void gather_kernel(
    const unsigned short* __restrict__ h, int nl,
    const unsigned short* __restrict__ wsk_g,
    unsigned short* __restrict__ skipacc, int skip_rd, int do_final,
    const float* __restrict__ bsum,
    const unsigned short* __restrict__ p1, const float* __restrict__ p1b,
    const unsigned short* __restrict__ p2, const float* __restrict__ p2b,
    float* __restrict__ out) {
  __shared__ short buf[2][128 * PADR];   // 69,632 B

  const int tid = threadIdx.x;
  const int b   = blockIdx.x >> 7;
  const int t0  = (blockIdx.x & 127) << 7;
  const int lane = tid & 63;
  const int n = lane & 15, q = lane >> 4;
  const int wv = tid >> 6;
  const int c0w = (wv & 1) * 64, t0w = (wv >> 1) * 64;
  const size_t tilebase = ((size_t)b * TLEN + t0) * RD;
  const size_t XNE = (size_t)NB * TLEN * RD;

  f32x4 acc[4][4];
  zero_acc(acc);
  int rows[4];
#pragma unroll
  for (int tt = 0; tt < 4; ++tt) rows[tt] = t0w + tt * 16 + n;

  if (nl > 0) {
    stage_tile(buf[0], h + tilebase, tid);
    __syncthreads();
    for (int li = 0; li < nl; ++li) {
      const int cur = li & 1;
      if (li + 1 < nl)
        stage_tile(buf[cur ^ 1], h + (size_t)(li + 1) * XNE + tilebase, tid);
      gemm128<true>(wsk_g + (size_t)li * RD * RD, buf[cur], rows, c0w, n, q, acc);
      __syncthreads();
    }
  }

  if (skip_rd) {
    const unsigned short* sp = skipacc + tilebase;
#pragma unroll
    for (int ct = 0; ct < 4; ++ct) {
      const int c = c0w + ct * 16 + n;
#pragma unroll
      for (int tt = 0; tt < 4; ++tt) {
        const int tb = t0w + tt * 16 + q * 4;
#pragma unroll
        for (int r = 0; r < 4; ++r)
          acc[ct][tt][r] += bf2f(sp[(size_t)(tb + r) * RD + c]);
      }
    }
  }

  if (!do_final) {   // write bf16 skipacc
    unsigned short* sp = skipacc + tilebase;
#pragma unroll
    for (int ct = 0; ct < 4; ++ct) {
      const int c = c0w + ct * 16 + n;
#pragma unroll
      for (int tt = 0; tt < 4; ++tt) {
        const int tb = t0w + tt * 16 + q * 4;
#pragma unroll
        for (int r = 0; r < 4; ++r)
          sp[(size_t)(tb + r) * RD + c] = f2bf(acc[ct][tt][r]);
      }
    }
    return;
  }

  // relu(skip + bsum) -> buf0 ; post1 ; relu -> buf1
  store_act(buf[0], acc, bsum, c0w, t0w, n, q);
  __syncthreads();
  zero_acc(acc);
  gemm128<true>(p1, buf[0], rows, c0w, n, q, acc);
  store_act(buf[1], acc, p1b, c0w, t0w, n, q);
  __syncthreads();

  // post2 halves, reversed orientation -> D[c][t], coalesced [C][T] stores
  for (int half = 0; half < 2; ++half) {
    zero_acc(acc);
    gemm128<false>(p2 + (size_t)half * RD * RD, buf[1], rows, c0w, n, q, acc);
    const size_t obase = ((size_t)b * QD + half * RD) * TLEN + t0;
#pragma unroll
    for (int ct = 0; ct < 4; ++ct) {
      const int cb = c0w + ct * 16 + q * 4;
      const float4 bb = *(const float4*)&p2b[half * RD + cb];
      const float bv[4] = {bb.x, bb.y, bb.z, bb.w};
#pragma unroll
      for (int tt = 0; tt < 4; ++tt) {
        const int t = t0w + tt * 16 + n;
#pragma unroll
        for (int r = 0; r < 4; ++r)
          out[obase + (size_t)(cb + r) * TLEN + t] = acc[ct][tt][r] + bv[r];
      }
    }
  }
}

// ---------------------------------------------------------------------------
// Causal conv: x [B,1,T] -> bf16 hi/lo planes [B][T][C]
// ---------------------------------------------------------------------------
__global__ __launch_bounds__(256) void causal_kernel(const float* __restrict__ x,
                                                     const float* __restrict__ w,
                                                     const float* __restrict__ bias,
                                                     unsigned short* __restrict__ hi,
                                                     unsigned short* __restrict__ lo) {
  __shared__ float xw[152];
  __shared__ float wl[RD * 25];
  __shared__ float bl[RD];
  const int tid = threadIdx.x;
  const int b   = blockIdx.x >> 7;
  const int t0  = (blockIdx.x & 127) << 7;
  for (int i = tid; i < RD * 25; i += 256) wl[i] = w[i];
  if (tid < RD) bl[tid] = bias[tid];
  for (int i = tid; i < 152; i += 256) {
    const int tg = t0 - 12 + i;
    xw[i] = ((unsigned)tg < (unsigned)TLEN) ? x[(size_t)b * TLEN + tg] : 0.f;
  }
  __syncthreads();
  const int c = tid & 127, tp = tid >> 7;
  unsigned short* hib = hi + ((size_t)b * TLEN + t0) * RD + c;
  unsigned short* lob = lo + ((size_t)b * TLEN + t0) * RD + c;
  const float bc = bl[c];
  for (int i = 0; i < 64; ++i) {
    const int tl = i * 2 + tp;
    float s = bc;
#pragma unroll
    for (int k = 0; k < 25; ++k) s = fmaf(wl[c * 25 + k], xw[tl + k], s);
    const unsigned short hv = f2bf(s);
    hib[(size_t)tl * RD] = hv;
    lob[(size_t)tl * RD] = f2bf(s - bf2f(hv));
  }
}

// ---------------------------------------------------------------------------
// Weight prep
// ---------------------------------------------------------------------------
__global__ __launch_bounds__(256) void cvt_kernel(const float* __restrict__ in,
                                                  unsigned short* __restrict__ out,
                                                  int total) {
  const int i = blockIdx.x * 256 + threadIdx.x;
  if (i < total) out[i] = f2bf(in[i]);
}
// dcnn: [L][co][ci][3] -> [L][3][co][ci]
__global__ __launch_bounds__(256) void cvt_conv_kernel(const float* __restrict__ in,
                                                       unsigned short* __restrict__ out,
                                                       int total) {
  const int idx = blockIdx.x * 256 + threadIdx.x;
  if (idx >= total) return;
  const int ci = idx & 127, co = (idx >> 7) & 127, lk = idx >> 14;
  const int k = lk % 3, l = lk / 3;
  out[idx] = f2bf(in[(((size_t)l * RD + co) * RD + ci) * 3 + k]);
}
__global__ void bsum_kernel(const float* __restrict__ sb, float* __restrict__ bsum) {
  const int c = threadIdx.x;
  float s = 0.f;
  for (int l = N0SKIP; l < NLAYER; ++l) s += sb[l * RD + c];
  bsum[c] = s;
}

// ---------------------------------------------------------------------------
extern "C" void kernel_launch(void* const* d_in, const int* in_sizes, int n_in,
                              void* d_out, int out_size, void* d_ws, size_t ws_size,
                              hipStream_t stream) {
  const float* x        = (const float*)d_in[0];
  const float* causal_w = (const float*)d_in[1];
  const float* causal_b = (const float*)d_in[2];
  const float* dcnn_w   = (const float*)d_in[3];
  const float* dcnn_b   = (const float*)d_in[4];
  const float* dense_w  = (const float*)d_in[5];
  const float* dense_b  = (const float*)d_in[6];
  const float* skip_w   = (const float*)d_in[7];
  const float* skip_b   = (const float*)d_in[8];
  const float* post1_w  = (const float*)d_in[9];
  const float* post1_b  = (const float*)d_in[10];
  const float* post2_w  = (const float*)d_in[11];
  const float* post2_b  = (const float*)d_in[12];
  float* out = (float*)d_out;

  const size_t XNE = (size_t)NB * TLEN * RD;   // 16.78M elems

  char* p = (char*)d_ws;
  float* bsm = (float*)p;                    p += 512;
  unsigned short* wc  = (unsigned short*)p;  p += (size_t)NLAYER * 3 * RD * RD * 2;
  unsigned short* wd  = (unsigned short*)p;  p += (size_t)NLAYER * RD * RD * 2;
  unsigned short* wsk = (unsigned short*)p;  p += (size_t)NLAYER * RD * RD * 2;
  unsigned short* p1  = (unsigned short*)p;  p += RD * RD * 2;
  unsigned short* p2  = (unsigned short*)p;  p += QD * RD * 2;
  unsigned short* hiA = (unsigned short*)p;  p += XNE * 2;
  unsigned short* hiB = (unsigned short*)p;  p += XNE * 2;
  unsigned short* loA = (unsigned short*)p;  p += XNE * 2;
  unsigned short* loB = (unsigned short*)p;  p += XNE * 2;
  const size_t base_used = (size_t)(p - (char*)d_ws);

  // tiering: how many h-buffers fit?
  int G = 0;
  unsigned short* skipacc = nullptr;
  unsigned short* hb = nullptr;
  if (ws_size >= base_used + (size_t)NSKIP * XNE * 2) {
    G = NSKIP;
    hb = (unsigned short*)p;
  } else {
    skipacc = (unsigned short*)p; p += XNE * 2;
    const size_t avail = (ws_size > (size_t)(p - (char*)d_ws))
                             ? ws_size - (size_t)(p - (char*)d_ws) : 0;
    G = (int)(avail / (XNE * 2));
    if (G > NSKIP - 1) G = NSKIP - 1;
    if (G > 0) hb = (unsigned short*)p;
  }

  const int tconv = NLAYER * 3 * RD * RD;
  const int t2    = NLAYER * RD * RD;
  cvt_conv_kernel<<<(tconv + 255) / 256, 256, 0, stream>>>(dcnn_w, wc, tconv);
  cvt_kernel<<<(t2 + 255) / 256, 256, 0, stream>>>(dense_w, wd, t2);
  cvt_kernel<<<(t2 + 255) / 256, 256, 0, stream>>>(skip_w, wsk, t2);
  cvt_kernel<<<(RD * RD + 255) / 256, 256, 0, stream>>>(post1_w, p1, RD * RD);
  cvt_kernel<<<(QD * RD + 255) / 256, 256, 0, stream>>>(post2_w, p2, QD * RD);
  if (G > 0) bsum_kernel<<<1, RD, 0, stream>>>(skip_b, bsm);
  else       hipMemsetAsync(bsm, 0, 512, stream);       // biases added per-layer
  if (G == 0) hipMemsetAsync(skipacc, 0, XNE * 2, stream);

  const int grid = NB * (TLEN / TT);
  causal_kernel<<<grid, 256, 0, stream>>>(x, causal_w, causal_b, hiA, loA);

  const unsigned short* his = hiA;  unsigned short* hid = hiB;
  const unsigned short* los = loA;  unsigned short* lod = loB;

  int done = 0, pending = 0;
  for (int l = 0; l < NLAYER; ++l) {
    const int dil = 1 << (l % 9);
    unsigned short* hout = nullptr;
    unsigned short* skarg = nullptr;
    if (l >= N0SKIP) {
      if (G > 0) hout = hb + (size_t)pending * XNE;
      else       skarg = skipacc;
    }
    layer_kernel<<<grid, 256, 0, stream>>>(
        his, los, hid, lod, hout, skarg,
        wc  + (size_t)l * 3 * RD * RD, dcnn_b  + (size_t)l * RD,
        wd  + (size_t)l * RD * RD,     dense_b + (size_t)l * RD,
        wsk + (size_t)l * RD * RD,     skip_b  + (size_t)l * RD,
        dil);
    { const unsigned short* t = his; his = hid; hid = (unsigned short*)t; }
    { const unsigned short* t = los; los = lod; lod = (unsigned short*)t; }

    if (l >= N0SKIP && G > 0) {
      ++pending;
      const int last = (l == NLAYER - 1);
      if (pending == G || last) {
        gather_kernel<<<grid, 256, 0, stream>>>(
            hb, pending, wsk + (size_t)(N0SKIP + done) * RD * RD,
            skipacc, (done > 0) ? 1 : 0, last,
            bsm, p1, post1_b, p2, post2_b, out);
        done += pending;
        pending = 0;
      }
    }
  }

  if (G == 0) {
    gather_kernel<<<grid, 256, 0, stream>>>(
        nullptr, 0, nullptr, skipacc, 1, 1,
        bsm, p1, post1_b, p2, post2_b, out);
  }
}